// Round 18
// baseline (8379.441 us; speedup 1.0000x reference)
//
#include <hip/hip_runtime.h>
#include <cstdint>

constexpr int B = 32, ET = 1024, DT = 1024, D = 256, PAD = 15, PT = ET + 2*PAD;
constexpr int NT = 32;                 // 32 t-tiles of 32 per batch
constexpr float LOG2E = 1.4426950408889634f;

typedef __attribute__((ext_vector_type(4))) float f32x4;
typedef __attribute__((ext_vector_type(4))) unsigned int uint4v;
typedef __attribute__((ext_vector_type(8))) __bf16 bf16x8;

// ws float layout (double-buffered by step parity; NO atomics, NO barriers)
constexpr size_t PBUF_OFF = 0;                            // [B][2 par][2 ch][PT] ch0=raw, ch1=cum
constexpr size_t PART_OFF = PBUF_OFF + (size_t)B*4*PT;    // [B][2 par][NT][D] raw PV partials
constexpr size_t SSUM_OFF = PART_OFF + (size_t)B*2*NT*D;  // [B][2 par][NT] raw tile sums
constexpr size_t WF_OFF   = SSUM_OFF + (size_t)B*2*NT;    // A-frag table, 16384 floats:
// [16 dtile][2 ch][2 split][64 lane][8 bf16]  (A[d][k]: lane = (d&15) + 16*(k/8), elem = k%8)

__global__ __launch_bounds__(256) void k_init(const float* __restrict__ W,
                                              float* __restrict__ ws) {
  int i0 = blockIdx.x*256 + threadIdx.x;
  int stride = gridDim.x*256;
  for (int i = i0; i < B*4*PT; i += stride) ws[PBUF_OFF + i] = 0.f;
  for (int i = i0; i < B*2*NT*D; i += stride) ws[PART_OFF + i] = 0.f;
  for (int i = i0; i < B*2*NT; i += stride) ws[SSUM_OFF + i] = 1.f/NT;  // Z(step0)=1
  // A-fragment table: hi/lo bf16 (truncation split) of W, zero-padded tap 31
  for (int i = i0; i < 16*2*2*64*8; i += stride) {
    int j = i & 7, lane = (i >> 3) & 63, split = (i >> 9) & 1,
        ch = (i >> 10) & 1, dt = i >> 11;
    int d = dt*16 + (lane & 15);
    int koff = (lane >> 4)*8 + j;
    float val = (koff < 31) ? W[d*62 + ch*31 + koff] : 0.f;
    unsigned bits = __float_as_uint(val);
    unsigned hb = bits & 0xFFFF0000u;
    unsigned half;
    if (split == 0) half = bits >> 16;
    else            half = __float_as_uint(val - __uint_as_float(hb)) >> 16;
    ((unsigned short*)(ws + WF_OFF))[i] = (unsigned short)half;
  }
}

__device__ __forceinline__ f32x4 mfma16(uint4v a, uint4v b, f32x4 c) {
  return __builtin_amdgcn_mfma_f32_16x16x32_bf16(
      __builtin_bit_cast(bf16x8, a), __builtin_bit_cast(bf16x8, b), c, 0, 0, 0);
}

// One decoder step. Reads parity p state (published by step-1), writes parity p^1.
// Kernel boundary provides all cross-block synchronization.
__global__ __attribute__((amdgpu_flat_work_group_size(256, 256), amdgpu_waves_per_eu(2, 4)))
void k_step(
    const float* __restrict__ enc,   // [B][ET][D]
    const float* __restrict__ mel,   // [B][DT][D]
    const int* __restrict__ elen, const int* __restrict__ olen,
    const float* __restrict__ vw,    // [D]
    float* __restrict__ ws,
    float* __restrict__ out_att,     // [B][DT][D]
    float* __restrict__ out_sc,      // [B][DT][ET]
    int step) {
  const int tid = threadIdx.x;
  const int lane = tid & 63;
  const int wq = __builtin_amdgcn_readfirstlane(tid >> 6);  // wave id 0..3
  const int bid = blockIdx.x;
  const int xcd = bid & 7, slot = bid >> 3;                 // slot 0..127
  const int b = ((slot & 3) << 3) | xcd;                    // L2-locality heuristic
  const int tile = slot >> 2;                               // 0..31
  const int t0 = tile * 32;
  const int p = step & 1, np = p ^ 1;

  float* pb = ws + PBUF_OFF + (size_t)b*4*PT;
  const float* raw_p = pb + (size_t)(p*2 + 0)*PT;
  const float* cum_p = pb + (size_t)(p*2 + 1)*PT;
  float* raw_n = pb + (size_t)(np*2 + 0)*PT;
  float* cum_n = pb + (size_t)(np*2 + 1)*PT;
  const float* part_p = ws + PART_OFF + ((size_t)b*2 + p)*NT*D;
  float*       part_n = ws + PART_OFF + ((size_t)b*2 + np)*NT*D;
  const float* S_p = ws + SSUM_OFF + (b*2 + p)*NT;
  float*       S_n = ws + SSUM_OFF + (b*2 + np)*NT;

  __shared__ float s_pa[64], s_pc[64], s_sc[NT];
  __shared__ unsigned s_P[4][64];   // packed bf16-pair windows: a-hi, a-lo, c-hi, c-lo
  __shared__ __align__(16) float u_lds[256], v_lds[256];
  __shared__ __align__(16) float s_part[NT][20];

  const int L = elen[b];
  const int OL = olen[b];

  // ---- A-fragments: independent of all state -> issue at kernel entry so
  // L2 latency hides under staging (they're consumed after the barrier) ----
  const uint4v* ap = (const uint4v*)(ws + WF_OFF);
  uint4v Afr[4][4];
#pragma unroll
  for (int dti = 0; dti < 4; ++dti) {
    const int dt = wq*4 + dti;
    Afr[dti][0] = ap[((dt*2 + 0)*2 + 0)*64 + lane];   // ch0 hi
    Afr[dti][1] = ap[((dt*2 + 0)*2 + 1)*64 + lane];   // ch0 lo
    Afr[dti][2] = ap[((dt*2 + 1)*2 + 0)*64 + lane];   // ch1 hi
    Afr[dti][3] = ap[((dt*2 + 1)*2 + 1)*64 + lane];   // ch1 lo
  }

  // ---- normalization of step-1 state: 1 load + 5 shuffles (was 32 loads) ----
  float zv = S_p[lane & 31];
#pragma unroll
  for (int m = 1; m < 32; m <<= 1) zv += __shfl_xor(zv, m, 64);
  const float Zinv = __builtin_amdgcn_rcpf(zv);

  // u[d=tid] = mel*dm + att_out(step-1);  att_out = (sum part~)/Z
  float usum = 0.f;
#pragma unroll
  for (int j = 0; j < NT; ++j) usum += part_p[j*D + tid];
  usum *= Zinv;
  if (tile == 0 && step > 0) {
    float dmp = (step-1 < OL) ? 1.f : 0.f;
    out_att[((size_t)b*DT + step-1)*D + tid] = usum * dmp;
  }
  const float dm = (step < OL) ? 1.f : 0.f;
  u_lds[tid] = fmaf(mel[((size_t)b*DT + step)*D + tid], dm, usum); // u[d=tid]
  v_lds[tid] = vw[tid];

  // ---- stage conv windows + pre-packed bf16 hi/lo pairs (one wave) ----
  // win[x] = value at absolute t = t0 + x - 15;  P[x] = {bf16(win[x+1]), bf16(win[x])}
  if (tid < 64) {
    int ix = t0 + tid; if (ix > PT-1) ix = PT-1;
    float rv = raw_p[ix];
    float sc = (ix < L + PAD) ? rv * Zinv : 0.f;   // mask AFTER softmax (ref order)
    float wc = cum_p[ix] + sc;
    s_pa[tid] = sc;
    s_pc[tid] = wc;
    unsigned ba = __float_as_uint(sc);
    unsigned ha = ba >> 16;
    unsigned la = __float_as_uint(sc - __uint_as_float(ba & 0xFFFF0000u)) >> 16;
    unsigned bc = __float_as_uint(wc);
    unsigned hc = bc >> 16;
    unsigned lc = __float_as_uint(wc - __uint_as_float(bc & 0xFFFF0000u)) >> 16;
    unsigned haN = __shfl_down(ha, 1, 64);   // neighbor win[x+1] (lane 63 unused)
    unsigned laN = __shfl_down(la, 1, 64);
    unsigned hcN = __shfl_down(hc, 1, 64);
    unsigned lcN = __shfl_down(lc, 1, 64);
    s_P[0][tid] = (haN << 16) | ha;
    s_P[1][tid] = (laN << 16) | la;
    s_P[2][tid] = (hcN << 16) | hc;
    s_P[3][tid] = (lcN << 16) | lc;
  }
  __syncthreads();

  // ---- conv via MFMA (split-bf16); B-frags are plain LDS u32 reads ----
  // frag elem pair jj covers koff = tq*8+2jj{,+1}; value = win[tc + tt*16 + koff]
  const int tq = lane >> 4, tc = lane & 15;
  const int xb = tc + tq*8;
  const unsigned msk3 = (tq == 3) ? 0x0000FFFFu : ~0u;  // zero tap k=31 (elem 7 of tq3)
  uint4v Bf[2][2][2];   // [tt][ch][split]
#pragma unroll
  for (int tt = 0; tt < 2; ++tt)
#pragma unroll
    for (int ch = 0; ch < 2; ++ch)
#pragma unroll
      for (int sp = 0; sp < 2; ++sp) {
        const unsigned* P = s_P[ch*2 + sp];
        const int x0 = xb + tt*16;
        uint4v f;
        f[0] = P[x0];
        f[1] = P[x0 + 2];
        f[2] = P[x0 + 4];
        f[3] = P[x0 + 6] & msk3;
        Bf[tt][ch][sp] = f;
      }

  float ep0 = 0.f, ep1 = 0.f;
#pragma unroll
  for (int dti = 0; dti < 4; ++dti) {
    const int dt = wq*4 + dti;      // this wave's d-tile (16 d rows)
    const int du = dt*16 + (lane >> 4)*4;            // C rows this lane holds
    f32x4 u4 = *(const f32x4*)&u_lds[du];
    f32x4 v4 = *(const f32x4*)&v_lds[du];
#pragma unroll
    for (int tt = 0; tt < 2; ++tt) {
      f32x4 acc = u4;                              // C-in carries u: s = u + conv
      acc = mfma16(Afr[dti][0], Bf[tt][0][0], acc);   // hi*hi ch0
      acc = mfma16(Afr[dti][1], Bf[tt][0][0], acc);   // lo*hi ch0
      acc = mfma16(Afr[dti][0], Bf[tt][0][1], acc);   // hi*lo ch0
      acc = mfma16(Afr[dti][2], Bf[tt][1][0], acc);   // hi*hi ch1
      acc = mfma16(Afr[dti][3], Bf[tt][1][0], acc);   // lo*hi ch1
      acc = mfma16(Afr[dti][2], Bf[tt][1][1], acc);   // hi*lo ch1
      float ep = 0.f;
#pragma unroll
      for (int r = 0; r < 4; ++r) {
        float s = acc[r];
        // v*tanh(s), tanh(s) = 1 - 2/(exp(2s)+1)
        float ex = __builtin_amdgcn_exp2f(s * (2.f*LOG2E));
        float th = fmaf(-2.f, __builtin_amdgcn_rcpf(ex + 1.f), 1.f);
        ep = fmaf(v4[r], th, ep);
      }
      if (tt == 0) ep0 += ep; else ep1 += ep;
    }
  }
  // partial energies: 16 per t (4 waves x 4 row-quads)
  s_part[lane & 15][(wq << 2) | (lane >> 4)] = ep0;
  s_part[16 + (lane & 15)][(wq << 2) | (lane >> 4)] = ep1;
  __syncthreads();

  // ---- energies -> raw exp (NO max-sub: |e| <= sum|v| ~12); publish ----
  if (tid < NT) {
    const float4 r0 = *(const float4*)&s_part[tid][0];
    const float4 r1 = *(const float4*)&s_part[tid][4];
    const float4 r2 = *(const float4*)&s_part[tid][8];
    const float4 r3 = *(const float4*)&s_part[tid][12];
    float e = (((r0.x+r0.y)+(r0.z+r0.w)) + ((r1.x+r1.y)+(r1.z+r1.w)))
            + (((r2.x+r2.y)+(r2.z+r2.w)) + ((r3.x+r3.y)+(r3.z+r3.w)));
    float raw = __builtin_amdgcn_exp2f(e * LOG2E);
    const int t = t0 + tid;
    raw_n[PAD + t] = raw;                         // raw score state
    s_sc[tid] = (t < L) ? raw : 0.f;              // masked raw for PV
    float ts = raw;                               // tile sum over ALL t (denominator)
#pragma unroll
    for (int msk = 1; msk < NT; msk <<= 1) ts += __shfl_xor(ts, msk, 64);
    if (tid == 0) S_n[tile] = ts;
    cum_n[PAD + t] = s_pc[tid + 15];              // cum through step-1 (owner slice)
    if (step > 0)
      out_sc[((size_t)b*DT + step-1)*ET + t] = s_pa[tid + 15];  // delayed score write
  }
  __syncthreads();

  // ---- PV with raw scores (normalized at consumption next step) ----
  if (t0 < L) {
    const float* eb = enc + ((size_t)b*ET + t0)*D + tid;
    float a0 = 0.f, a1 = 0.f, a2 = 0.f, a3 = 0.f;
    for (int r = 0; r < 32; r += 4) {
      a0 = fmaf(s_sc[r],   eb[(size_t)r*D],     a0);
      a1 = fmaf(s_sc[r+1], eb[(size_t)(r+1)*D], a1);
      a2 = fmaf(s_sc[r+2], eb[(size_t)(r+2)*D], a2);
      a3 = fmaf(s_sc[r+3], eb[(size_t)(r+3)*D], a3);
    }
    part_n[tile*D + tid] = (a0 + a1) + (a2 + a3);
  }
}

// epilogue: normalize+write outputs of the final step
__global__ __launch_bounds__(256) void k_fin(
    const int* __restrict__ elen, const int* __restrict__ olen,
    const float* __restrict__ ws,
    float* __restrict__ out_att, float* __restrict__ out_sc) {
  const int tid = threadIdx.x;
  const int bid = blockIdx.x;
  const int xcd = bid & 7, slot = bid >> 3;
  const int b = ((slot & 3) << 3) | xcd;
  const int tile = slot >> 2;
  const int t0 = tile * 32;
  const int p = DT & 1;   // parity holding step DT-1's published state

  const float* raw_p = ws + PBUF_OFF + (size_t)b*4*PT + (size_t)(p*2)*PT;
  const float* part_p = ws + PART_OFF + ((size_t)b*2 + p)*NT*D;
  const float* S_p = ws + SSUM_OFF + (b*2 + p)*NT;
  const int L = elen[b];
  const int OL = olen[b];

  float z = 0.f;
#pragma unroll
  for (int j = 0; j < NT; ++j) z += S_p[j];
  const float Zinv = 1.f / z;

  if (tile == 0) {
    float usum = 0.f;
#pragma unroll
    for (int j = 0; j < NT; ++j) usum += part_p[j*D + tid];
    float dmp = (DT-1 < OL) ? 1.f : 0.f;
    out_att[((size_t)b*DT + DT-1)*D + tid] = usum * Zinv * dmp;
  }
  if (tid < 32) {
    const int t = t0 + tid;
    float rv = raw_p[PAD + t];
    out_sc[((size_t)b*DT + DT-1)*ET + t] = (t < L) ? rv * Zinv : 0.f;
  }
}

extern "C" void kernel_launch(void* const* d_in, const int* in_sizes, int n_in,
                              void* d_out, int out_size, void* d_ws, size_t ws_size,
                              hipStream_t stream) {
  const float* enc = (const float*)d_in[0];
  const float* mel = (const float*)d_in[1];
  const int* elen  = (const int*)d_in[2];
  const int* olen  = (const int*)d_in[3];
  const float* vw  = (const float*)d_in[4];   // [1, D]
  const float* W   = (const float*)d_in[5];   // [D, 2, KW]

  float* out_att = (float*)d_out;                 // [B, DT, D]
  float* out_sc  = out_att + (size_t)B*DT*D;      // [B, DT, ET]
  float* ws = (float*)d_ws;

  k_init<<<128, 256, 0, stream>>>(W, ws);
  for (int step = 0; step < DT; ++step)
    k_step<<<1024, 256, 0, stream>>>(enc, mel, elen, olen, vw, ws,
                                     out_att, out_sc, step);
  k_fin<<<1024, 256, 0, stream>>>(elen, olen, ws, out_att, out_sc);
}

// Round 19
// 7489.379 us; speedup vs baseline: 1.1188x; 1.1188x over previous
//
#include <hip/hip_runtime.h>
#include <cstdint>

constexpr int B = 32, ET = 1024, DT = 1024, D = 256, PAD = 15, PT = ET + 2*PAD;
constexpr int NT = 32;                 // 32 t-tiles of 32 per batch
constexpr float LOG2E = 1.4426950408889634f;

typedef __attribute__((ext_vector_type(4))) float f32x4;
typedef __attribute__((ext_vector_type(4))) unsigned int uint4v;
typedef __attribute__((ext_vector_type(8))) __bf16 bf16x8;

// ws float layout (double-buffered by step parity; NO atomics, NO barriers)
constexpr size_t PBUF_OFF = 0;                            // [B][2 par][2 ch][PT] ch0=raw(masked), ch1=cum
constexpr size_t PART_OFF = PBUF_OFF + (size_t)B*4*PT;    // [B][2 par][NT][D] raw PV partials
constexpr size_t SSUM_OFF = PART_OFF + (size_t)B*2*NT*D;  // [B][2 par][NT] raw tile sums
constexpr size_t WF_OFF   = SSUM_OFF + (size_t)B*2*NT;    // A-frag table, 16384 floats:
// [16 dtile][2 ch][2 split][64 lane][8 bf16]; ch0 = Wa+Wc (raw channel), ch1 = Wc (cum channel)

__global__ __launch_bounds__(256) void k_init(const float* __restrict__ W,
                                              float* __restrict__ ws) {
  int i0 = blockIdx.x*256 + threadIdx.x;
  int stride = gridDim.x*256;
  for (int i = i0; i < B*4*PT; i += stride) ws[PBUF_OFF + i] = 0.f;
  for (int i = i0; i < B*2*NT*D; i += stride) ws[PART_OFF + i] = 0.f;
  for (int i = i0; i < B*2*NT; i += stride) ws[SSUM_OFF + i] = 1.f/NT;  // Z(step0)=1
  // A-fragment table: hi/lo bf16 (truncation split); ch0 = Wa+Wc, ch1 = Wc; tap 31 = 0
  for (int i = i0; i < 16*2*2*64*8; i += stride) {
    int j = i & 7, lane = (i >> 3) & 63, split = (i >> 9) & 1,
        ch = (i >> 10) & 1, dt = i >> 11;
    int d = dt*16 + (lane & 15);
    int koff = (lane >> 4)*8 + j;
    float val = 0.f;
    if (koff < 31) {
      float wa = W[d*62 + koff], wc = W[d*62 + 31 + koff];
      val = ch ? wc : (wa + wc);
    }
    unsigned bits = __float_as_uint(val);
    unsigned hb = bits & 0xFFFF0000u;
    unsigned half;
    if (split == 0) half = bits >> 16;
    else            half = __float_as_uint(val - __uint_as_float(hb)) >> 16;
    ((unsigned short*)(ws + WF_OFF))[i] = (unsigned short)half;
  }
}

__device__ __forceinline__ f32x4 mfma16(uint4v a, uint4v b, f32x4 c) {
  return __builtin_amdgcn_mfma_f32_16x16x32_bf16(
      __builtin_bit_cast(bf16x8, a), __builtin_bit_cast(bf16x8, b), c, 0, 0, 0);
}

// One decoder step. Reads parity p state (published by step-1), writes parity p^1.
// Kernel boundary provides all cross-block synchronization.
// s = mel*dm + Zinv*(usum + conv(raw, Wa+Wc)) + conv(cum_old, Wc)  -- Z off the
// critical path: staging/pack/MFMA never wait on the Z reduce.
__global__ __attribute__((amdgpu_flat_work_group_size(256, 256), amdgpu_waves_per_eu(2, 4)))
void k_step(
    const float* __restrict__ enc,   // [B][ET][D]
    const float* __restrict__ mel,   // [B][DT][D]
    const int* __restrict__ elen, const int* __restrict__ olen,
    const float* __restrict__ vw,    // [D]
    float* __restrict__ ws,
    float* __restrict__ out_att,     // [B][DT][D]
    float* __restrict__ out_sc,      // [B][DT][ET]
    int step) {
  const int tid = threadIdx.x;
  const int lane = tid & 63;
  const int wq = __builtin_amdgcn_readfirstlane(tid >> 6);  // wave id 0..3
  const int bid = blockIdx.x;
  const int xcd = bid & 7, slot = bid >> 3;                 // slot 0..127
  const int b = ((slot & 3) << 3) | xcd;                    // L2-locality heuristic
  const int tile = slot >> 2;                               // 0..31
  const int t0 = tile * 32;
  const int p = step & 1, np = p ^ 1;

  float* pb = ws + PBUF_OFF + (size_t)b*4*PT;
  const float* raw_p = pb + (size_t)(p*2 + 0)*PT;
  const float* cum_p = pb + (size_t)(p*2 + 1)*PT;
  float* raw_n = pb + (size_t)(np*2 + 0)*PT;
  float* cum_n = pb + (size_t)(np*2 + 1)*PT;
  const float* part_p = ws + PART_OFF + ((size_t)b*2 + p)*NT*D;
  float*       part_n = ws + PART_OFF + ((size_t)b*2 + np)*NT*D;
  const float* S_p = ws + SSUM_OFF + (b*2 + p)*NT;
  float*       S_n = ws + SSUM_OFF + (b*2 + np)*NT;

  __shared__ float s_pa[64], s_pc[64], s_sc[NT];
  __shared__ unsigned s_P[4][64];   // packed bf16-pair windows: raw-hi, raw-lo, cum-hi, cum-lo
  __shared__ __align__(16) float u_lds[256], m_lds[256], v_lds[256];
  __shared__ __align__(16) float s_part[NT][20];

  const int L = elen[b];
  const int OL = olen[b];

  // ---- stage conv windows + pre-packed bf16 hi/lo pairs (one wave) ----
  // raw_p is already masked (publish-time mask) -> no Zinv, no mask here.
  // win[x] = value at absolute t = t0 + x - 15;  P[x] = {bf16(win[x+1]), bf16(win[x])}
  if (tid < 64) {
    int ix = t0 + tid; if (ix > PT-1) ix = PT-1;
    float rv = raw_p[ix];
    float cv = cum_p[ix];
    s_pa[tid] = rv;
    s_pc[tid] = cv;
    unsigned ba = __float_as_uint(rv);
    unsigned ha = ba >> 16;
    unsigned la = __float_as_uint(rv - __uint_as_float(ba & 0xFFFF0000u)) >> 16;
    unsigned bc = __float_as_uint(cv);
    unsigned hc = bc >> 16;
    unsigned lc = __float_as_uint(cv - __uint_as_float(bc & 0xFFFF0000u)) >> 16;
    unsigned haN = __shfl_down(ha, 1, 64);   // neighbor win[x+1] (lane 63 unused)
    unsigned laN = __shfl_down(la, 1, 64);
    unsigned hcN = __shfl_down(hc, 1, 64);
    unsigned lcN = __shfl_down(lc, 1, 64);
    s_P[0][tid] = (haN << 16) | ha;
    s_P[1][tid] = (laN << 16) | la;
    s_P[2][tid] = (hcN << 16) | hc;
    s_P[3][tid] = (lcN << 16) | lc;
  }

  // ---- Z reduce (consumed only in epilogue): 1 load + 5 shuffles ----
  float zv = S_p[lane & 31];
#pragma unroll
  for (int m = 1; m < 32; m <<= 1) zv += __shfl_xor(zv, m, 64);
  const float Zinv = __builtin_amdgcn_rcpf(zv);

  // ---- usum (RAW, normalized in epilogue) + mel mask ----
  float usum = 0.f;
#pragma unroll
  for (int j = 0; j < NT; ++j) usum += part_p[j*D + tid];
  if (tile == 0 && step > 0) {
    float dmp = (step-1 < OL) ? 1.f : 0.f;
    out_att[((size_t)b*DT + step-1)*D + tid] = usum * Zinv * dmp;
  }
  const float dm = (step < OL) ? 1.f : 0.f;
  u_lds[tid] = usum;                                        // raw part-sum
  m_lds[tid] = mel[((size_t)b*DT + step)*D + tid] * dm;     // mel*dm
  v_lds[tid] = vw[tid];
  __syncthreads();

  // ---- conv via MFMA (split-bf16); B-frags are plain LDS u32 reads ----
  const int tq = lane >> 4, tc = lane & 15;
  const int xb = tc + tq*8;
  const unsigned msk3 = (tq == 3) ? 0x0000FFFFu : ~0u;  // zero tap k=31 (elem 7 of tq3)
  uint4v Bf[2][2][2];   // [tt][ch][split]  ch0=raw, ch1=cum
#pragma unroll
  for (int tt = 0; tt < 2; ++tt)
#pragma unroll
    for (int ch = 0; ch < 2; ++ch)
#pragma unroll
      for (int sp = 0; sp < 2; ++sp) {
        const unsigned* P = s_P[ch*2 + sp];
        const int x0 = xb + tt*16;
        uint4v f;
        f[0] = P[x0];
        f[1] = P[x0 + 2];
        f[2] = P[x0 + 4];
        f[3] = P[x0 + 6] & msk3;
        Bf[tt][ch][sp] = f;
      }

  const uint4v* ap = (const uint4v*)(ws + WF_OFF);
  float ep0 = 0.f, ep1 = 0.f;
#pragma unroll
  for (int dti = 0; dti < 4; ++dti) {
    const int dt = wq*4 + dti;      // this wave's d-tile (16 d rows)
    uint4v a0h = ap[((dt*2 + 0)*2 + 0)*64 + lane];   // Ws hi (raw channel)
    uint4v a0l = ap[((dt*2 + 0)*2 + 1)*64 + lane];   // Ws lo
    uint4v a1h = ap[((dt*2 + 1)*2 + 0)*64 + lane];   // Wc hi (cum channel)
    uint4v a1l = ap[((dt*2 + 1)*2 + 1)*64 + lane];   // Wc lo
    const int du = dt*16 + (lane >> 4)*4;            // C rows this lane holds
    f32x4 u4 = *(const f32x4*)&u_lds[du];
    f32x4 m4 = *(const f32x4*)&m_lds[du];
    f32x4 v4 = *(const f32x4*)&v_lds[du];
#pragma unroll
    for (int tt = 0; tt < 2; ++tt) {
      f32x4 accA = u4;   // raw channel, scaled by Zinv in epilogue (carries usum)
      f32x4 accC = m4;   // cum channel + mel*dm
      accA = mfma16(a0h, Bf[tt][0][0], accA);   // Ws_hi * raw_hi
      accC = mfma16(a1h, Bf[tt][1][0], accC);   // Wc_hi * cum_hi
      accA = mfma16(a0l, Bf[tt][0][0], accA);   // Ws_lo * raw_hi
      accC = mfma16(a1l, Bf[tt][1][0], accC);   // Wc_lo * cum_hi
      accA = mfma16(a0h, Bf[tt][0][1], accA);   // Ws_hi * raw_lo
      accC = mfma16(a1h, Bf[tt][1][1], accC);   // Wc_hi * cum_lo
      float ep = 0.f;
#pragma unroll
      for (int r = 0; r < 4; ++r) {
        float s = fmaf(Zinv, accA[r], accC[r]);
        // v*tanh(s), tanh(s) = 1 - 2/(exp(2s)+1)
        float ex = __builtin_amdgcn_exp2f(s * (2.f*LOG2E));
        float th = fmaf(-2.f, __builtin_amdgcn_rcpf(ex + 1.f), 1.f);
        ep = fmaf(v4[r], th, ep);
      }
      if (tt == 0) ep0 += ep; else ep1 += ep;
    }
  }
  // partial energies: 16 per t (4 waves x 4 row-quads)
  s_part[lane & 15][(wq << 2) | (lane >> 4)] = ep0;
  s_part[16 + (lane & 15)][(wq << 2) | (lane >> 4)] = ep1;
  __syncthreads();

  // ---- energies -> raw exp (NO max-sub: |e| <= sum|v| ~12); publish ----
  if (tid < NT) {
    const float4 r0 = *(const float4*)&s_part[tid][0];
    const float4 r1 = *(const float4*)&s_part[tid][4];
    const float4 r2 = *(const float4*)&s_part[tid][8];
    const float4 r3 = *(const float4*)&s_part[tid][12];
    float e = (((r0.x+r0.y)+(r0.z+r0.w)) + ((r1.x+r1.y)+(r1.z+r1.w)))
            + (((r2.x+r2.y)+(r2.z+r2.w)) + ((r3.x+r3.y)+(r3.z+r3.w)));
    float raw = __builtin_amdgcn_exp2f(e * LOG2E);
    const int t = t0 + tid;
    float ts = raw;                               // denominator sums UNMASKED raw
#pragma unroll
    for (int msk = 1; msk < NT; msk <<= 1) ts += __shfl_xor(ts, msk, 64);
    if (tid == 0) S_n[tile] = ts;
    float rm = (t < L) ? raw : 0.f;               // publish-time mask
    raw_n[PAD + t] = rm;                          // masked raw score state
    s_sc[tid] = rm;                               // masked raw for PV
    cum_n[PAD + t] = fmaf(s_pa[tid + 15], Zinv, s_pc[tid + 15]); // cum thru step-1
    if (step > 0)
      out_sc[((size_t)b*DT + step-1)*ET + t] = s_pa[tid + 15] * Zinv; // delayed write
  }
  __syncthreads();

  // ---- PV with raw scores (normalized at consumption next step) ----
  if (t0 < L) {
    const float* eb = enc + ((size_t)b*ET + t0)*D + tid;
    float a0 = 0.f, a1 = 0.f, a2 = 0.f, a3 = 0.f;
    for (int r = 0; r < 32; r += 4) {
      a0 = fmaf(s_sc[r],   eb[(size_t)r*D],     a0);
      a1 = fmaf(s_sc[r+1], eb[(size_t)(r+1)*D], a1);
      a2 = fmaf(s_sc[r+2], eb[(size_t)(r+2)*D], a2);
      a3 = fmaf(s_sc[r+3], eb[(size_t)(r+3)*D], a3);
    }
    part_n[tile*D + tid] = (a0 + a1) + (a2 + a3);
  }
}

// epilogue: normalize+write outputs of the final step
__global__ __launch_bounds__(256) void k_fin(
    const int* __restrict__ elen, const int* __restrict__ olen,
    const float* __restrict__ ws,
    float* __restrict__ out_att, float* __restrict__ out_sc) {
  const int tid = threadIdx.x;
  const int bid = blockIdx.x;
  const int xcd = bid & 7, slot = bid >> 3;
  const int b = ((slot & 3) << 3) | xcd;
  const int tile = slot >> 2;
  const int t0 = tile * 32;
  const int p = DT & 1;   // parity holding step DT-1's published state

  const float* raw_p = ws + PBUF_OFF + (size_t)b*4*PT + (size_t)(p*2)*PT;
  const float* part_p = ws + PART_OFF + ((size_t)b*2 + p)*NT*D;
  const float* S_p = ws + SSUM_OFF + (b*2 + p)*NT;
  const int L = elen[b];
  const int OL = olen[b];

  float z = 0.f;
#pragma unroll
  for (int j = 0; j < NT; ++j) z += S_p[j];
  const float Zinv = 1.f / z;

  if (tile == 0) {
    float usum = 0.f;
#pragma unroll
    for (int j = 0; j < NT; ++j) usum += part_p[j*D + tid];
    float dmp = (DT-1 < OL) ? 1.f : 0.f;
    out_att[((size_t)b*DT + DT-1)*D + tid] = usum * Zinv * dmp;
  }
  if (tid < 32) {
    const int t = t0 + tid;
    float rv = raw_p[PAD + t];          // already masked at publish
    out_sc[((size_t)b*DT + DT-1)*ET + t] = rv * Zinv;
  }
}

extern "C" void kernel_launch(void* const* d_in, const int* in_sizes, int n_in,
                              void* d_out, int out_size, void* d_ws, size_t ws_size,
                              hipStream_t stream) {
  const float* enc = (const float*)d_in[0];
  const float* mel = (const float*)d_in[1];
  const int* elen  = (const int*)d_in[2];
  const int* olen  = (const int*)d_in[3];
  const float* vw  = (const float*)d_in[4];   // [1, D]
  const float* W   = (const float*)d_in[5];   // [D, 2, KW]

  float* out_att = (float*)d_out;                 // [B, DT, D]
  float* out_sc  = out_att + (size_t)B*DT*D;      // [B, DT, ET]
  float* ws = (float*)d_ws;

  k_init<<<128, 256, 0, stream>>>(W, ws);
  for (int step = 0; step < DT; ++step)
    k_step<<<1024, 256, 0, stream>>>(enc, mel, elen, olen, vw, ws,
                                     out_att, out_sc, step);
  k_fin<<<1024, 256, 0, stream>>>(elen, olen, ws, out_att, out_sc);
}